// Round 22
// baseline (263.393 us; speedup 1.0000x reference)
//
#include <hip/hip_runtime.h>
#include <hip/hip_bf16.h>
#include <math.h>

// GanDTI forward. B=4096, N_ATOMS=50, FEAT=40, GNN_DEPTH=3, MLP_DEPTH=2.
//
// k_main (r20 bodies, reordered grid — FIXED r21 OOB): 6400 blocks x 256 thr.
//   blk <  256:        p256 job (16 samples) — fronted.
//   256 <= blk < 4352: pairs [GNN, stream]: even e -> GNN job e/2 (0..2047),
//                      odd e -> stream chunk e/2 (0..2047).
//   4352 <= blk < 6400: stream chunks 2048..4095 (pure-HBM tail).
//   (r21 launched 6656 blocks -> stream chunks up to 4351 -> OOB. Fixed.)
//   GNN: 2x8 tile, comp stride 44 / h stride 40, Wg LDS-staged w/ reg prefetch.
// k_tail (r13/r16 verbatim): 1024 blocks x 256 thr, G=4.

#define BATCH 4096
#define SC 44   // comp row stride
#define SH 40   // h row stride

// ===================== k_main =====================
__global__ __launch_bounds__(256) void k_main(
    const int* __restrict__ atoms, const float* __restrict__ A,
    const float* __restrict__ A69, const float* __restrict__ emb,
    const float* __restrict__ Wg, const float* __restrict__ bg,
    const float* __restrict__ W1, const float* __restrict__ b1,
    const float* __restrict__ W2,
    const float* __restrict__ protein, const float* __restrict__ W3,
    const float* __restrict__ b3,
    float* __restrict__ ws_cv, float* __restrict__ ws_part,
    float* __restrict__ ws_p256)
{
    __shared__ float sm[10000];  // comp[2][2200] @0, h[2][2000] @4400, wg[1600] @8400
    const int tid  = threadIdx.x;
    const int blk  = blockIdx.x;
    const int lane = tid & 63, wv = tid >> 6;
    const int c0   = lane * 4;

    int gnn_job = -1, stream_cid = -1, p256_sid = -1;
    if (blk < 256) {
        p256_sid = blk;
    } else if (blk < 4352) {
        const int e = blk - 256;
        if ((e & 1) == 0) gnn_job = e >> 1;
        else              stream_cid = e >> 1;
    } else {
        stream_cid = 2048 + (blk - 4352);
        if (stream_cid >= 4096) return;      // defensive bound
    }

    if (p256_sid >= 0) {
        // ---------- p256: 16 samples/block, 4 per wave ----------
        const int b0 = p256_sid * 16 + wv * 4;
        float acc[4][4];
        #pragma unroll
        for (int s = 0; s < 4; ++s)
            #pragma unroll
            for (int c = 0; c < 4; ++c) acc[s][c] = 0.f;
        const float* prot = protein + (size_t)b0 * 512;
        for (int j4 = 0; j4 < 128; ++j4) {
            float pv[4][4];
            #pragma unroll
            for (int s = 0; s < 4; ++s)
                *(float4*)pv[s] = *(const float4*)(prot + (size_t)s * 512 + j4 * 4);
            #pragma unroll
            for (int u = 0; u < 4; ++u) {
                float w3v[4];
                *(float4*)w3v = *(const float4*)(W3 + (size_t)(j4 * 4 + u) * 256 + c0);
                #pragma unroll
                for (int s = 0; s < 4; ++s)
                    #pragma unroll
                    for (int c = 0; c < 4; ++c)
                        acc[s][c] = fmaf(pv[s][u], w3v[c], acc[s][c]);
            }
        }
        float b3v[4];
        *(float4*)b3v = *(const float4*)(b3 + c0);
        #pragma unroll
        for (int s = 0; s < 4; ++s) {
            float o[4];
            #pragma unroll
            for (int c = 0; c < 4; ++c) o[c] = acc[s][c] + b3v[c];
            *(float4*)(ws_p256 + (size_t)(b0 + s) * 256 + c0) = *(float4*)o;
        }
        return;
    }

    if (stream_cid >= 0) {
        // ---------- stream: partial a256, 8 samples x 128-k chunk ----------
        const int kc = stream_cid & 7, sg = stream_cid >> 3;
        const int s0 = sg * 8, k0 = kc * 128;
        float* a69s = sm;    // [64][10]

        float w1r[30];
        #pragma unroll
        for (int k = 0; k < 15; ++k) {
            float2 t = ((const float2*)W1)[k];
            w1r[2 * k] = t.x; w1r[2 * k + 1] = t.y;
        }
        const float b1v = b1[0];

        float acc[2][4] = {{0.f,0.f,0.f,0.f},{0.f,0.f,0.f,0.f}};

        for (int h = 0; h < 2; ++h) {
            const int base = k0 + h * 64;
            const int nrh = (1001 - base < 64) ? (1001 - base) : 64;
            if (h) __syncthreads();
            for (int idx = tid; idx < 512; idx += 256) {
                const int s = idx >> 6, rr = idx & 63;
                if (rr < nrh) {
                    const float2* p = (const float2*)(A69 + ((size_t)(s0 + s) * 1001 + base + rr) * 30);
                    float v = b1v;
                    #pragma unroll
                    for (int k = 0; k < 15; ++k) {
                        float2 q = p[k];
                        v = fmaf(q.x, w1r[2 * k], v);
                        v = fmaf(q.y, w1r[2 * k + 1], v);
                    }
                    a69s[rr * 10 + s] = v;
                }
            }
            __syncthreads();
            for (int k = 0; k < nrh; ++k) {
                const float a0 = a69s[k * 10 + wv * 2];
                const float a1 = a69s[k * 10 + wv * 2 + 1];
                float w2v[4];
                *(float4*)w2v = *(const float4*)(W2 + (size_t)(base + k) * 256 + c0);
                #pragma unroll
                for (int c = 0; c < 4; ++c) {
                    acc[0][c] = fmaf(a0, w2v[c], acc[0][c]);
                    acc[1][c] = fmaf(a1, w2v[c], acc[1][c]);
                }
            }
        }
        #pragma unroll
        for (int s = 0; s < 2; ++s)
            *(float4*)(ws_part + ((size_t)kc * BATCH + s0 + wv * 2 + s) * 256 + c0) = *(float4*)acc[s];
        return;
    }

    // ================= GNN: 2 samples/block, Wg LDS-staged =================
    const int job = gnn_job;
    const int smp = tid >> 7;
    const int t   = tid & 127;
    const int b   = job * 2 + smp;

    float* comp = sm + smp * 2200;            // [50][SC]
    float* h_s  = sm + 4400 + smp * 2000;     // [50][SH]
    float* wg_s = sm + 8400;                  // [40][40], shared by both samples

    for (int idx = tid; idx < 1000; idx += 256) {
        const int s_ = idx / 500, rem = idx - s_ * 500;
        const int n = rem / 10, f4 = rem - n * 10;
        const int row = atoms[(job * 2 + s_) * 50 + n];
        *(float4*)(sm + s_ * 2200 + n * SC + f4 * 4) = *(const float4*)(emb + row * 40 + f4 * 4);
    }
    *(float4*)(wg_s + tid * 4) = *(const float4*)(Wg + tid * 4);
    if (tid < 144) *(float4*)(wg_s + 1024 + tid * 4) = *(const float4*)(Wg + 1024 + tid * 4);
    __syncthreads();

    float res_sum = 0.f;
    if (tid < 80) {
        const int s_ = tid / 40, col = tid - s_ * 40;
        const float* c_ = sm + s_ * 2200;
        for (int n = 0; n < 50; ++n) res_sum += c_[n * SC + col];
    }

    const int rg = t / 5;
    const int cg = t - rg * 5;
    const int n0 = rg * 2, f0 = cg * 8;
    const bool act = (t < 125);
    const float* Ab = A + (size_t)b * 2500;

    for (int l = 0; l < 3; ++l) {
        float4 wgp0, wgp1;
        if (l < 2) {
            wgp0 = *(const float4*)(Wg + (l + 1) * 1600 + tid * 4);
            if (tid < 144) wgp1 = *(const float4*)(Wg + (l + 1) * 1600 + 1024 + tid * 4);
        }
        if (act) {
            // ---- m1: h = leaky(comp @ wg_s + bg[l]) — Wg from LDS ----
            float bgv[8];
            *(float4*)bgv       = *(const float4*)(bg + l * 40 + f0);
            *(float4*)(bgv + 4) = *(const float4*)(bg + l * 40 + f0 + 4);
            float acc0[8], acc1[8];
            #pragma unroll
            for (int c = 0; c < 8; ++c) { acc0[c] = bgv[c]; acc1[c] = bgv[c]; }
            #pragma unroll
            for (int j4 = 0; j4 < 10; ++j4) {
                float c0a[4], c1a[4];
                *(float4*)c0a = *(float4*)(comp + n0 * SC + j4 * 4);
                *(float4*)c1a = *(float4*)(comp + n0 * SC + SC + j4 * 4);
                #pragma unroll
                for (int u = 0; u < 4; ++u) {
                    float w8[8];
                    *(float4*)w8       = *(float4*)(wg_s + (j4 * 4 + u) * 40 + f0);
                    *(float4*)(w8 + 4) = *(float4*)(wg_s + (j4 * 4 + u) * 40 + f0 + 4);
                    #pragma unroll
                    for (int c = 0; c < 8; ++c) {
                        acc0[c] = fmaf(c0a[u], w8[c], acc0[c]);
                        acc1[c] = fmaf(c1a[u], w8[c], acc1[c]);
                    }
                }
            }
            float h0[8], h1[8];
            #pragma unroll
            for (int c = 0; c < 8; ++c) {
                h0[c] = acc0[c] > 0.f ? acc0[c] : 0.01f * acc0[c];
                h1[c] = acc1[c] > 0.f ? acc1[c] : 0.01f * acc1[c];
            }
            *(float4*)(h_s + n0 * SH + f0)          = *(float4*)h0;
            *(float4*)(h_s + n0 * SH + f0 + 4)      = *(float4*)(h0 + 4);
            *(float4*)(h_s + n0 * SH + SH + f0)     = *(float4*)h1;
            *(float4*)(h_s + n0 * SH + SH + f0 + 4) = *(float4*)(h1 + 4);
        }
        __syncthreads();   // h ready; wg_s dead until next layer's m1
        if (l < 2) {
            *(float4*)(wg_s + tid * 4) = wgp0;
            if (tid < 144) *(float4*)(wg_s + 1024 + tid * 4) = wgp1;
        }
        if (act) {
            // ---- m2: comp += A @ h (A from global; h same-row broadcast) ----
            float acc0[8], acc1[8];
            #pragma unroll
            for (int c = 0; c < 8; ++c) { acc0[c] = 0.f; acc1[c] = 0.f; }
            #pragma unroll
            for (int m4 = 0; m4 < 12; ++m4) {
                float a0a[4], a1a[4];
                *(float4*)a0a       = *(const float4*)(Ab + n0 * 50 + m4 * 4);
                *(float2*)a1a       = *(const float2*)(Ab + (n0 + 1) * 50 + m4 * 4);
                *(float2*)(a1a + 2) = *(const float2*)(Ab + (n0 + 1) * 50 + m4 * 4 + 2);
                #pragma unroll
                for (int u = 0; u < 4; ++u) {
                    float h8[8];
                    *(float4*)h8       = *(float4*)(h_s + (m4 * 4 + u) * SH + f0);
                    *(float4*)(h8 + 4) = *(float4*)(h_s + (m4 * 4 + u) * SH + f0 + 4);
                    #pragma unroll
                    for (int c = 0; c < 8; ++c) {
                        acc0[c] = fmaf(a0a[u], h8[c], acc0[c]);
                        acc1[c] = fmaf(a1a[u], h8[c], acc1[c]);
                    }
                }
            }
            {
                float h48[8], h49[8];
                *(float4*)h48       = *(float4*)(h_s + 48 * SH + f0);
                *(float4*)(h48 + 4) = *(float4*)(h_s + 48 * SH + f0 + 4);
                *(float4*)h49       = *(float4*)(h_s + 49 * SH + f0);
                *(float4*)(h49 + 4) = *(float4*)(h_s + 49 * SH + f0 + 4);
                const float a048 = Ab[n0 * 50 + 48], a049 = Ab[n0 * 50 + 49];
                const float a148 = Ab[(n0 + 1) * 50 + 48], a149 = Ab[(n0 + 1) * 50 + 49];
                #pragma unroll
                for (int c = 0; c < 8; ++c) {
                    acc0[c] = fmaf(a048, h48[c], acc0[c]);
                    acc0[c] = fmaf(a049, h49[c], acc0[c]);
                    acc1[c] = fmaf(a148, h48[c], acc1[c]);
                    acc1[c] = fmaf(a149, h49[c], acc1[c]);
                }
            }
            float c0a[8], c1a[8];
            *(float4*)c0a       = *(float4*)(comp + n0 * SC + f0);
            *(float4*)(c0a + 4) = *(float4*)(comp + n0 * SC + f0 + 4);
            *(float4*)c1a       = *(float4*)(comp + n0 * SC + SC + f0);
            *(float4*)(c1a + 4) = *(float4*)(comp + n0 * SC + SC + f0 + 4);
            #pragma unroll
            for (int c = 0; c < 8; ++c) { c0a[c] += acc0[c]; c1a[c] += acc1[c]; }
            *(float4*)(comp + n0 * SC + f0)          = *(float4*)c0a;
            *(float4*)(comp + n0 * SC + f0 + 4)      = *(float4*)(c0a + 4);
            *(float4*)(comp + n0 * SC + SC + f0)     = *(float4*)c1a;
            *(float4*)(comp + n0 * SC + SC + f0 + 4) = *(float4*)(c1a + 4);
        }
        __syncthreads();
    }

    if (tid < 80) {
        const int s_ = tid / 40, col = tid - s_ * 40;
        const float* c_ = sm + s_ * 2200;
        float s = res_sum;
        for (int n = 0; n < 50; ++n) s += c_[n * SC + col];
        ws_cv[(size_t)(job * 2 + s_) * 40 + col] = s * 0.02f;
    }
}

// ===================== k_tail (r13/r16 verbatim) =====================
__global__ __launch_bounds__(256) void k_tail(
    const float* __restrict__ b2,
    const float* __restrict__ Wp, const float* __restrict__ bp,
    const float* __restrict__ Watt, const float* __restrict__ batt,
    const float* __restrict__ Wm, const float* __restrict__ bm,
    const float* __restrict__ Wo, const float* __restrict__ bo,
    const float* __restrict__ ws_cv, const float* __restrict__ ws_part,
    const float* __restrict__ ws_p256, float* __restrict__ out)
{
    const int G = 4, PC = 520;
    __shared__ float pc[4 * 520];
    __shared__ float p40s[4 * 40];
    __shared__ float phs[4 * 40];
    __shared__ float wts[4];
    __shared__ float cps[2][4 * 84];
    const int tid  = threadIdx.x;
    const int lane = tid & 63, wv = tid >> 6;
    const int b0   = blockIdx.x * G;
    const int c0   = lane * 4;

    {
        const int g = wv;
        float b2v[4];
        *(float4*)b2v = *(const float4*)(b2 + c0);
        float o[4] = {b2v[0], b2v[1], b2v[2], b2v[3]};
        #pragma unroll
        for (int kc = 0; kc < 8; ++kc) {
            float pv[4];
            *(float4*)pv = *(const float4*)(ws_part + ((size_t)kc * BATCH + b0 + g) * 256 + c0);
            #pragma unroll
            for (int c = 0; c < 4; ++c) o[c] += pv[c];
        }
        *(float4*)(pc + g * PC + c0) = *(float4*)o;
        *(float4*)(pc + g * PC + 256 + c0) =
            *(const float4*)(ws_p256 + (size_t)(b0 + g) * 256 + c0);
    }
    __syncthreads();

    if (tid < 160) {
        const int g = tid / 40, f = tid - (tid / 40) * 40;
        float s = bp[f];
        for (int j4 = 0; j4 < 128; ++j4) {
            float pv[4];
            *(float4*)pv = *(float4*)(pc + g * PC + j4 * 4);
            #pragma unroll
            for (int u = 0; u < 4; ++u)
                s = fmaf(pv[u], Wp[(j4 * 4 + u) * 40 + f], s);
        }
        p40s[g * 40 + f] = s;
    }
    __syncthreads();

    if (tid < 160) {
        const int g = tid / 40, f = tid - (tid / 40) * 40;
        float s = batt[f];
        #pragma unroll
        for (int j4 = 0; j4 < 10; ++j4) {
            float pv[4];
            *(float4*)pv = *(float4*)(p40s + g * 40 + j4 * 4);
            #pragma unroll
            for (int u = 0; u < 4; ++u)
                s = fmaf(pv[u], Watt[(j4 * 4 + u) * 40 + f], s);
        }
        phs[tid] = s > 0.f ? s : 0.f;
    }
    __syncthreads();

    if (tid < G) {
        float m = 0.f;
        #pragma unroll
        for (int f4 = 0; f4 < 10; ++f4) {
            float cv[4], ph[4];
            *(float4*)cv = *(const float4*)(ws_cv + (size_t)(b0 + tid) * 40 + f4 * 4);
            *(float4*)ph = *(float4*)(phs + tid * 40 + f4 * 4);
            #pragma unroll
            for (int c = 0; c < 4; ++c) m = fmaf(cv[c], ph[c], m);
        }
        wts[tid] = tanhf(m);
    }
    __syncthreads();

    for (int it = tid; it < G * 80; it += 256) {
        const int g = it / 80, f = it - (it / 80) * 80;
        const float v = (f < 40) ? ws_cv[(size_t)(b0 + g) * 40 + f]
                                 : wts[g] * phs[g * 40 + (f - 40)];
        cps[0][g * 84 + f] = v;
    }
    __syncthreads();

    int cb = 0;
    for (int l = 0; l < 2; ++l) {
        for (int it = tid; it < G * 80; it += 256) {
            const int g = it / 80, kk = it - (it / 80) * 80;
            float s = bm[l * 80 + kk];
            #pragma unroll
            for (int j4 = 0; j4 < 20; ++j4) {
                float cv[4];
                *(float4*)cv = *(float4*)(cps[cb] + g * 84 + j4 * 4);
                #pragma unroll
                for (int u = 0; u < 4; ++u)
                    s = fmaf(cv[u], Wm[l * 6400 + (j4 * 4 + u) * 80 + kk], s);
            }
            cps[cb ^ 1][g * 84 + kk] = s > 0.f ? s : 0.f;
        }
        __syncthreads();
        cb ^= 1;
    }
    if (tid < G) {
        float s = bo[0];
        #pragma unroll
        for (int j4 = 0; j4 < 20; ++j4) {
            float cv[4], wo[4];
            *(float4*)cv = *(float4*)(cps[cb] + tid * 84 + j4 * 4);
            *(float4*)wo = *(const float4*)(Wo + j4 * 4);
            #pragma unroll
            for (int u = 0; u < 4; ++u) s = fmaf(cv[u], wo[u], s);
        }
        out[b0 + tid] = s;
    }
}

extern "C" void kernel_launch(void* const* d_in, const int* in_sizes, int n_in,
                              void* d_out, int out_size, void* d_ws, size_t ws_size,
                              hipStream_t stream) {
    const int*   atoms   = (const int*)d_in[0];
    const float* A       = (const float*)d_in[1];
    const float* A69     = (const float*)d_in[2];
    const float* protein = (const float*)d_in[3];
    const float* emb     = (const float*)d_in[4];
    const float* Wg      = (const float*)d_in[5];
    const float* bg      = (const float*)d_in[6];
    const float* Watt    = (const float*)d_in[7];
    const float* batt    = (const float*)d_in[8];
    const float* W1      = (const float*)d_in[9];
    const float* b1      = (const float*)d_in[10];
    const float* W2      = (const float*)d_in[11];
    const float* b2      = (const float*)d_in[12];
    const float* W3      = (const float*)d_in[13];
    const float* b3      = (const float*)d_in[14];
    const float* Wp      = (const float*)d_in[15];
    const float* bp      = (const float*)d_in[16];
    const float* Wm      = (const float*)d_in[17];
    const float* bm      = (const float*)d_in[18];
    const float* Wo      = (const float*)d_in[19];
    const float* bo      = (const float*)d_in[20];

    float* ws_cv   = (float*)d_ws;                           // [4096][40]
    float* ws_part = ws_cv + (size_t)BATCH * 40;             // [8][4096][256]
    float* ws_p256 = ws_part + (size_t)8 * BATCH * 256;      // [4096][256]
    float* outp    = (float*)d_out;

    k_main<<<dim3(6400), dim3(256), 0, stream>>>(
        atoms, A, A69, emb, Wg, bg, W1, b1, W2, protein, W3, b3,
        ws_cv, ws_part, ws_p256);
    k_tail<<<dim3(1024), dim3(256), 0, stream>>>(
        b2, Wp, bp, Watt, batt, Wm, bm, Wo, bo,
        ws_cv, ws_part, ws_p256, outp);
}

// Round 23
// 254.572 us; speedup vs baseline: 1.0347x; 1.0347x over previous
//
#include <hip/hip_runtime.h>
#include <hip/hip_bf16.h>
#include <math.h>

// GanDTI forward. B=4096, N_ATOMS=50, FEAT=40, GNN_DEPTH=3, MLP_DEPTH=2.
// FINAL (= round-20 best, 254.8 us): r22's reorder regressed; reverted.
//
// k_main: 6528 blocks x 256 thr, [GNN,S,S] interleave.
//   GNN: 2 samples/block, 2x8 tile; comp stride 44, h stride 40 (40 KB LDS);
//        Wg LDS-staged with register prefetch across the h-barrier.
//   stream: sid<256 p256 (16 samples); else a256 partial chunk.
// k_tail: 1024 blocks x 256 thr, G=4.

#define BATCH 4096
#define SC 44   // comp row stride
#define SH 40   // h row stride

// ===================== k_main =====================
__global__ __launch_bounds__(256) void k_main(
    const int* __restrict__ atoms, const float* __restrict__ A,
    const float* __restrict__ A69, const float* __restrict__ emb,
    const float* __restrict__ Wg, const float* __restrict__ bg,
    const float* __restrict__ W1, const float* __restrict__ b1,
    const float* __restrict__ W2,
    const float* __restrict__ protein, const float* __restrict__ W3,
    const float* __restrict__ b3,
    float* __restrict__ ws_cv, float* __restrict__ ws_part,
    float* __restrict__ ws_p256)
{
    __shared__ float sm[10000];  // comp[2][2200] @0, h[2][2000] @4400, wg[1600] @8400
    const int tid  = threadIdx.x;
    const int blk  = blockIdx.x;
    const int lane = tid & 63, wv = tid >> 6;
    const int c0   = lane * 4;

    if (blk % 3 != 0) {
        const int sid = blk - blk / 3 - 1;    // 0..4351
        if (sid < 256) {
            // ---------- p256: 16 samples/block, 4 per wave ----------
            const int b0 = sid * 16 + wv * 4;
            float acc[4][4];
            #pragma unroll
            for (int s = 0; s < 4; ++s)
                #pragma unroll
                for (int c = 0; c < 4; ++c) acc[s][c] = 0.f;
            const float* prot = protein + (size_t)b0 * 512;
            for (int j4 = 0; j4 < 128; ++j4) {
                float pv[4][4];
                #pragma unroll
                for (int s = 0; s < 4; ++s)
                    *(float4*)pv[s] = *(const float4*)(prot + (size_t)s * 512 + j4 * 4);
                #pragma unroll
                for (int u = 0; u < 4; ++u) {
                    float w3v[4];
                    *(float4*)w3v = *(const float4*)(W3 + (size_t)(j4 * 4 + u) * 256 + c0);
                    #pragma unroll
                    for (int s = 0; s < 4; ++s)
                        #pragma unroll
                        for (int c = 0; c < 4; ++c)
                            acc[s][c] = fmaf(pv[s][u], w3v[c], acc[s][c]);
                }
            }
            float b3v[4];
            *(float4*)b3v = *(const float4*)(b3 + c0);
            #pragma unroll
            for (int s = 0; s < 4; ++s) {
                float o[4];
                #pragma unroll
                for (int c = 0; c < 4; ++c) o[c] = acc[s][c] + b3v[c];
                *(float4*)(ws_p256 + (size_t)(b0 + s) * 256 + c0) = *(float4*)o;
            }
            return;
        }
        // ---------- stream: partial a256, 8 samples x 128-k chunk ----------
        const int cid = sid - 256;
        const int kc = cid & 7, sg = cid >> 3;
        const int s0 = sg * 8, k0 = kc * 128;
        float* a69s = sm;    // [64][10]

        float w1r[30];
        #pragma unroll
        for (int k = 0; k < 15; ++k) {
            float2 t = ((const float2*)W1)[k];
            w1r[2 * k] = t.x; w1r[2 * k + 1] = t.y;
        }
        const float b1v = b1[0];

        float acc[2][4] = {{0.f,0.f,0.f,0.f},{0.f,0.f,0.f,0.f}};

        for (int h = 0; h < 2; ++h) {
            const int base = k0 + h * 64;
            const int nrh = (1001 - base < 64) ? (1001 - base) : 64;
            if (h) __syncthreads();
            for (int idx = tid; idx < 512; idx += 256) {
                const int s = idx >> 6, rr = idx & 63;
                if (rr < nrh) {
                    const float2* p = (const float2*)(A69 + ((size_t)(s0 + s) * 1001 + base + rr) * 30);
                    float v = b1v;
                    #pragma unroll
                    for (int k = 0; k < 15; ++k) {
                        float2 q = p[k];
                        v = fmaf(q.x, w1r[2 * k], v);
                        v = fmaf(q.y, w1r[2 * k + 1], v);
                    }
                    a69s[rr * 10 + s] = v;
                }
            }
            __syncthreads();
            for (int k = 0; k < nrh; ++k) {
                const float a0 = a69s[k * 10 + wv * 2];
                const float a1 = a69s[k * 10 + wv * 2 + 1];
                float w2v[4];
                *(float4*)w2v = *(const float4*)(W2 + (size_t)(base + k) * 256 + c0);
                #pragma unroll
                for (int c = 0; c < 4; ++c) {
                    acc[0][c] = fmaf(a0, w2v[c], acc[0][c]);
                    acc[1][c] = fmaf(a1, w2v[c], acc[1][c]);
                }
            }
        }
        #pragma unroll
        for (int s = 0; s < 2; ++s)
            *(float4*)(ws_part + ((size_t)kc * BATCH + s0 + wv * 2 + s) * 256 + c0) = *(float4*)acc[s];
        return;
    }

    // ================= GNN: 2 samples/block, Wg LDS-staged =================
    const int job = blk / 3;
    if (job >= 2048) return;
    const int smp = tid >> 7;
    const int t   = tid & 127;
    const int b   = job * 2 + smp;

    float* comp = sm + smp * 2200;            // [50][SC]
    float* h_s  = sm + 4400 + smp * 2000;     // [50][SH]
    float* wg_s = sm + 8400;                  // [40][40], shared by both samples

    for (int idx = tid; idx < 1000; idx += 256) {
        const int s_ = idx / 500, rem = idx - s_ * 500;
        const int n = rem / 10, f4 = rem - n * 10;
        const int row = atoms[(job * 2 + s_) * 50 + n];
        *(float4*)(sm + s_ * 2200 + n * SC + f4 * 4) = *(const float4*)(emb + row * 40 + f4 * 4);
    }
    *(float4*)(wg_s + tid * 4) = *(const float4*)(Wg + tid * 4);
    if (tid < 144) *(float4*)(wg_s + 1024 + tid * 4) = *(const float4*)(Wg + 1024 + tid * 4);
    __syncthreads();

    float res_sum = 0.f;
    if (tid < 80) {
        const int s_ = tid / 40, col = tid - s_ * 40;
        const float* c_ = sm + s_ * 2200;
        for (int n = 0; n < 50; ++n) res_sum += c_[n * SC + col];
    }

    const int rg = t / 5;
    const int cg = t - rg * 5;
    const int n0 = rg * 2, f0 = cg * 8;
    const bool act = (t < 125);
    const float* Ab = A + (size_t)b * 2500;

    for (int l = 0; l < 3; ++l) {
        float4 wgp0, wgp1;
        if (l < 2) {
            wgp0 = *(const float4*)(Wg + (l + 1) * 1600 + tid * 4);
            if (tid < 144) wgp1 = *(const float4*)(Wg + (l + 1) * 1600 + 1024 + tid * 4);
        }
        if (act) {
            // ---- m1: h = leaky(comp @ wg_s + bg[l]) — Wg from LDS ----
            float bgv[8];
            *(float4*)bgv       = *(const float4*)(bg + l * 40 + f0);
            *(float4*)(bgv + 4) = *(const float4*)(bg + l * 40 + f0 + 4);
            float acc0[8], acc1[8];
            #pragma unroll
            for (int c = 0; c < 8; ++c) { acc0[c] = bgv[c]; acc1[c] = bgv[c]; }
            #pragma unroll
            for (int j4 = 0; j4 < 10; ++j4) {
                float c0a[4], c1a[4];
                *(float4*)c0a = *(float4*)(comp + n0 * SC + j4 * 4);
                *(float4*)c1a = *(float4*)(comp + n0 * SC + SC + j4 * 4);
                #pragma unroll
                for (int u = 0; u < 4; ++u) {
                    float w8[8];
                    *(float4*)w8       = *(float4*)(wg_s + (j4 * 4 + u) * 40 + f0);
                    *(float4*)(w8 + 4) = *(float4*)(wg_s + (j4 * 4 + u) * 40 + f0 + 4);
                    #pragma unroll
                    for (int c = 0; c < 8; ++c) {
                        acc0[c] = fmaf(c0a[u], w8[c], acc0[c]);
                        acc1[c] = fmaf(c1a[u], w8[c], acc1[c]);
                    }
                }
            }
            float h0[8], h1[8];
            #pragma unroll
            for (int c = 0; c < 8; ++c) {
                h0[c] = acc0[c] > 0.f ? acc0[c] : 0.01f * acc0[c];
                h1[c] = acc1[c] > 0.f ? acc1[c] : 0.01f * acc1[c];
            }
            *(float4*)(h_s + n0 * SH + f0)          = *(float4*)h0;
            *(float4*)(h_s + n0 * SH + f0 + 4)      = *(float4*)(h0 + 4);
            *(float4*)(h_s + n0 * SH + SH + f0)     = *(float4*)h1;
            *(float4*)(h_s + n0 * SH + SH + f0 + 4) = *(float4*)(h1 + 4);
        }
        __syncthreads();   // h ready; wg_s dead until next layer's m1
        if (l < 2) {
            *(float4*)(wg_s + tid * 4) = wgp0;
            if (tid < 144) *(float4*)(wg_s + 1024 + tid * 4) = wgp1;
        }
        if (act) {
            // ---- m2: comp += A @ h (A from global; h same-row broadcast) ----
            float acc0[8], acc1[8];
            #pragma unroll
            for (int c = 0; c < 8; ++c) { acc0[c] = 0.f; acc1[c] = 0.f; }
            #pragma unroll
            for (int m4 = 0; m4 < 12; ++m4) {
                float a0a[4], a1a[4];
                *(float4*)a0a       = *(const float4*)(Ab + n0 * 50 + m4 * 4);
                *(float2*)a1a       = *(const float2*)(Ab + (n0 + 1) * 50 + m4 * 4);
                *(float2*)(a1a + 2) = *(const float2*)(Ab + (n0 + 1) * 50 + m4 * 4 + 2);
                #pragma unroll
                for (int u = 0; u < 4; ++u) {
                    float h8[8];
                    *(float4*)h8       = *(float4*)(h_s + (m4 * 4 + u) * SH + f0);
                    *(float4*)(h8 + 4) = *(float4*)(h_s + (m4 * 4 + u) * SH + f0 + 4);
                    #pragma unroll
                    for (int c = 0; c < 8; ++c) {
                        acc0[c] = fmaf(a0a[u], h8[c], acc0[c]);
                        acc1[c] = fmaf(a1a[u], h8[c], acc1[c]);
                    }
                }
            }
            {
                float h48[8], h49[8];
                *(float4*)h48       = *(float4*)(h_s + 48 * SH + f0);
                *(float4*)(h48 + 4) = *(float4*)(h_s + 48 * SH + f0 + 4);
                *(float4*)h49       = *(float4*)(h_s + 49 * SH + f0);
                *(float4*)(h49 + 4) = *(float4*)(h_s + 49 * SH + f0 + 4);
                const float a048 = Ab[n0 * 50 + 48], a049 = Ab[n0 * 50 + 49];
                const float a148 = Ab[(n0 + 1) * 50 + 48], a149 = Ab[(n0 + 1) * 50 + 49];
                #pragma unroll
                for (int c = 0; c < 8; ++c) {
                    acc0[c] = fmaf(a048, h48[c], acc0[c]);
                    acc0[c] = fmaf(a049, h49[c], acc0[c]);
                    acc1[c] = fmaf(a148, h48[c], acc1[c]);
                    acc1[c] = fmaf(a149, h49[c], acc1[c]);
                }
            }
            float c0a[8], c1a[8];
            *(float4*)c0a       = *(float4*)(comp + n0 * SC + f0);
            *(float4*)(c0a + 4) = *(float4*)(comp + n0 * SC + f0 + 4);
            *(float4*)c1a       = *(float4*)(comp + n0 * SC + SC + f0);
            *(float4*)(c1a + 4) = *(float4*)(comp + n0 * SC + SC + f0 + 4);
            #pragma unroll
            for (int c = 0; c < 8; ++c) { c0a[c] += acc0[c]; c1a[c] += acc1[c]; }
            *(float4*)(comp + n0 * SC + f0)          = *(float4*)c0a;
            *(float4*)(comp + n0 * SC + f0 + 4)      = *(float4*)(c0a + 4);
            *(float4*)(comp + n0 * SC + SC + f0)     = *(float4*)c1a;
            *(float4*)(comp + n0 * SC + SC + f0 + 4) = *(float4*)(c1a + 4);
        }
        __syncthreads();
    }

    if (tid < 80) {
        const int s_ = tid / 40, col = tid - s_ * 40;
        const float* c_ = sm + s_ * 2200;
        float s = res_sum;
        for (int n = 0; n < 50; ++n) s += c_[n * SC + col];
        ws_cv[(size_t)(job * 2 + s_) * 40 + col] = s * 0.02f;
    }
}

// ===================== k_tail (r13/r16 verbatim) =====================
__global__ __launch_bounds__(256) void k_tail(
    const float* __restrict__ b2,
    const float* __restrict__ Wp, const float* __restrict__ bp,
    const float* __restrict__ Watt, const float* __restrict__ batt,
    const float* __restrict__ Wm, const float* __restrict__ bm,
    const float* __restrict__ Wo, const float* __restrict__ bo,
    const float* __restrict__ ws_cv, const float* __restrict__ ws_part,
    const float* __restrict__ ws_p256, float* __restrict__ out)
{
    const int G = 4, PC = 520;
    __shared__ float pc[4 * 520];
    __shared__ float p40s[4 * 40];
    __shared__ float phs[4 * 40];
    __shared__ float wts[4];
    __shared__ float cps[2][4 * 84];
    const int tid  = threadIdx.x;
    const int lane = tid & 63, wv = tid >> 6;
    const int b0   = blockIdx.x * G;
    const int c0   = lane * 4;

    {
        const int g = wv;
        float b2v[4];
        *(float4*)b2v = *(const float4*)(b2 + c0);
        float o[4] = {b2v[0], b2v[1], b2v[2], b2v[3]};
        #pragma unroll
        for (int kc = 0; kc < 8; ++kc) {
            float pv[4];
            *(float4*)pv = *(const float4*)(ws_part + ((size_t)kc * BATCH + b0 + g) * 256 + c0);
            #pragma unroll
            for (int c = 0; c < 4; ++c) o[c] += pv[c];
        }
        *(float4*)(pc + g * PC + c0) = *(float4*)o;
        *(float4*)(pc + g * PC + 256 + c0) =
            *(const float4*)(ws_p256 + (size_t)(b0 + g) * 256 + c0);
    }
    __syncthreads();

    if (tid < 160) {
        const int g = tid / 40, f = tid - (tid / 40) * 40;
        float s = bp[f];
        for (int j4 = 0; j4 < 128; ++j4) {
            float pv[4];
            *(float4*)pv = *(float4*)(pc + g * PC + j4 * 4);
            #pragma unroll
            for (int u = 0; u < 4; ++u)
                s = fmaf(pv[u], Wp[(j4 * 4 + u) * 40 + f], s);
        }
        p40s[g * 40 + f] = s;
    }
    __syncthreads();

    if (tid < 160) {
        const int g = tid / 40, f = tid - (tid / 40) * 40;
        float s = batt[f];
        #pragma unroll
        for (int j4 = 0; j4 < 10; ++j4) {
            float pv[4];
            *(float4*)pv = *(float4*)(p40s + g * 40 + j4 * 4);
            #pragma unroll
            for (int u = 0; u < 4; ++u)
                s = fmaf(pv[u], Watt[(j4 * 4 + u) * 40 + f], s);
        }
        phs[tid] = s > 0.f ? s : 0.f;
    }
    __syncthreads();

    if (tid < G) {
        float m = 0.f;
        #pragma unroll
        for (int f4 = 0; f4 < 10; ++f4) {
            float cv[4], ph[4];
            *(float4*)cv = *(const float4*)(ws_cv + (size_t)(b0 + tid) * 40 + f4 * 4);
            *(float4*)ph = *(float4*)(phs + tid * 40 + f4 * 4);
            #pragma unroll
            for (int c = 0; c < 4; ++c) m = fmaf(cv[c], ph[c], m);
        }
        wts[tid] = tanhf(m);
    }
    __syncthreads();

    for (int it = tid; it < G * 80; it += 256) {
        const int g = it / 80, f = it - (it / 80) * 80;
        const float v = (f < 40) ? ws_cv[(size_t)(b0 + g) * 40 + f]
                                 : wts[g] * phs[g * 40 + (f - 40)];
        cps[0][g * 84 + f] = v;
    }
    __syncthreads();

    int cb = 0;
    for (int l = 0; l < 2; ++l) {
        for (int it = tid; it < G * 80; it += 256) {
            const int g = it / 80, kk = it - (it / 80) * 80;
            float s = bm[l * 80 + kk];
            #pragma unroll
            for (int j4 = 0; j4 < 20; ++j4) {
                float cv[4];
                *(float4*)cv = *(float4*)(cps[cb] + g * 84 + j4 * 4);
                #pragma unroll
                for (int u = 0; u < 4; ++u)
                    s = fmaf(cv[u], Wm[l * 6400 + (j4 * 4 + u) * 80 + kk], s);
            }
            cps[cb ^ 1][g * 84 + kk] = s > 0.f ? s : 0.f;
        }
        __syncthreads();
        cb ^= 1;
    }
    if (tid < G) {
        float s = bo[0];
        #pragma unroll
        for (int j4 = 0; j4 < 20; ++j4) {
            float cv[4], wo[4];
            *(float4*)cv = *(float4*)(cps[cb] + tid * 84 + j4 * 4);
            *(float4*)wo = *(const float4*)(Wo + j4 * 4);
            #pragma unroll
            for (int u = 0; u < 4; ++u) s = fmaf(cv[u], wo[u], s);
        }
        out[b0 + tid] = s;
    }
}

extern "C" void kernel_launch(void* const* d_in, const int* in_sizes, int n_in,
                              void* d_out, int out_size, void* d_ws, size_t ws_size,
                              hipStream_t stream) {
    const int*   atoms   = (const int*)d_in[0];
    const float* A       = (const float*)d_in[1];
    const float* A69     = (const float*)d_in[2];
    const float* protein = (const float*)d_in[3];
    const float* emb     = (const float*)d_in[4];
    const float* Wg      = (const float*)d_in[5];
    const float* bg      = (const float*)d_in[6];
    const float* Watt    = (const float*)d_in[7];
    const float* batt    = (const float*)d_in[8];
    const float* W1      = (const float*)d_in[9];
    const float* b1      = (const float*)d_in[10];
    const float* W2      = (const float*)d_in[11];
    const float* b2      = (const float*)d_in[12];
    const float* W3      = (const float*)d_in[13];
    const float* b3      = (const float*)d_in[14];
    const float* Wp      = (const float*)d_in[15];
    const float* bp      = (const float*)d_in[16];
    const float* Wm      = (const float*)d_in[17];
    const float* bm      = (const float*)d_in[18];
    const float* Wo      = (const float*)d_in[19];
    const float* bo      = (const float*)d_in[20];

    float* ws_cv   = (float*)d_ws;                           // [4096][40]
    float* ws_part = ws_cv + (size_t)BATCH * 40;             // [8][4096][256]
    float* ws_p256 = ws_part + (size_t)8 * BATCH * 256;      // [4096][256]
    float* outp    = (float*)d_out;

    k_main<<<dim3(6528), dim3(256), 0, stream>>>(
        atoms, A, A69, emb, Wg, bg, W1, b1, W2, protein, W3, b3,
        ws_cv, ws_part, ws_p256);
    k_tail<<<dim3(1024), dim3(256), 0, stream>>>(
        b2, Wp, bp, Watt, batt, Wm, bm, Wo, bo,
        ws_cv, ws_part, ws_p256, outp);
}